// Round 1
// baseline (290.581 us; speedup 1.0000x reference)
//
#include <hip/hip_runtime.h>
#include <hip/hip_bf16.h>

// Problem constants
#define B_ 8
#define T_ 8192
#define D_ 128
#define S_ 128
#define CK 64
#define NC 128           // T_/CK
#define NCHUNK (B_*NC)   // 1024

// ws layout (in floats)
#define WS_WT      0                       // 3 x [128][128]  WT_dt, WT_B, WT_C   ([d][s])
#define WS_WOUTT   49152                   // [128][128] WoutT  ([s][d])
#define WS_AVEC    65536                   // [128]
#define WS_ABUF    65664                   // B*T*S  a -> cumP (in-place)
#define WS_UBUF    (WS_ABUF + 8388608)     // B*T*S  u -> h_local (in-place)
#define WS_CBUF    (WS_UBUF + 8388608)     // B*T*S  C
#define WS_CARRYA  (WS_CBUF + 8388608)     // B*NC*S
#define WS_CARRYH  (WS_CARRYA + 131072)
#define WS_H0      (WS_CARRYH + 131072)
// total floats = WS_H0 + 131072 = 25,624,704  (~98 MB)

// ---------------- K0: transpose weights, precompute A ----------------
__global__ __launch_bounds__(256) void k0_prep(
    const float* __restrict__ Wdt, const float* __restrict__ WB,
    const float* __restrict__ WC,  const float* __restrict__ Wout,
    const float* __restrict__ logA, float* __restrict__ ws) {
  int p = blockIdx.x, tid = threadIdx.x;
  const float* src = (p == 0) ? Wdt : (p == 1) ? WB : (p == 2) ? WC : Wout;
  float* dst = ws + ((p < 3) ? p * 16384 : WS_WOUTT);
  for (int i = 0; i < 64; ++i) {
    int f = tid + 256 * i;        // 16384 elems
    int r = f >> 7, c = f & 127;
    dst[c * 128 + r] = src[f];    // transpose
  }
  if (p == 3 && tid < 128) {
    ws[WS_AVEC + tid] = -fminf(expf(logA[tid]), 10.0f);
  }
}

// ---------------- K1: projections + elementwise (a, u, C) ----------------
// one block per chunk; LDS: xsT [128][64] fp32 + wt [64][128] fp32 = 64 KB
__global__ __launch_bounds__(256) void k1_proj(
    const float* __restrict__ x, const float* __restrict__ bdt,
    float* __restrict__ ws) {
  __shared__ float xsT[128 * 64];   // [d][t]
  __shared__ float wt[64 * 128];    // [d-slice][s]
  const int tid = threadIdx.x;
  const int bc  = blockIdx.x;                 // b*NC + c
  const long xbase = (long)bc * (CK * D_);    // (b*T + c*CK)*D

  // load + transpose x tile (bank conflicts on write are one-time)
  const float4* x4 = (const float4*)(x + xbase);
#pragma unroll
  for (int i = 0; i < 8; ++i) {
    int f4 = tid + 256 * i;       // 0..2047
    int t  = f4 >> 5;
    int d0 = (f4 & 31) << 2;
    float4 v = x4[f4];
    xsT[(d0 + 0) * 64 + t] = v.x;
    xsT[(d0 + 1) * 64 + t] = v.y;
    xsT[(d0 + 2) * 64 + t] = v.z;
    xsT[(d0 + 3) * 64 + t] = v.w;
  }

  const int sg = tid & 31, s0 = sg << 2;   // 4 s per thread
  const int tg = tid >> 5, t0 = tg << 3;   // 8 t per thread

  float dtv[8][4];

  for (int p = 0; p < 3; ++p) {
    float acc[8][4];
#pragma unroll
    for (int i = 0; i < 8; ++i)
#pragma unroll
      for (int j = 0; j < 4; ++j) acc[i][j] = 0.0f;

    const float* WT = ws + p * 16384;   // [d][s]
    for (int ks = 0; ks < 2; ++ks) {
      __syncthreads();   // previous wt consumers done (also covers xsT writes)
      const float4* wsrc = (const float4*)(WT + ks * 64 * 128);
#pragma unroll
      for (int i = 0; i < 8; ++i)
        ((float4*)wt)[tid + 256 * i] = wsrc[tid + 256 * i];
      __syncthreads();

      for (int d = 0; d < 64; ++d) {
        float4 w4 = ((const float4*)wt)[d * 32 + sg];
        float4 xa = ((const float4*)xsT)[(ks * 64 + d) * 16 + tg * 2];
        float4 xb = ((const float4*)xsT)[(ks * 64 + d) * 16 + tg * 2 + 1];
        float xt[8] = {xa.x, xa.y, xa.z, xa.w, xb.x, xb.y, xb.z, xb.w};
        const float* wv = (const float*)&w4;
#pragma unroll
        for (int i = 0; i < 8; ++i)
#pragma unroll
          for (int j = 0; j < 4; ++j)
            acc[i][j] = fmaf(xt[i], wv[j], acc[i][j]);
      }
    }

    if (p == 0) {
      float4 bd = *(const float4*)(bdt + s0);
      float4 av = *(const float4*)(ws + WS_AVEC + s0);
      const float* bdp = (const float*)&bd;
      const float* avp = (const float*)&av;
      float* aBuf = ws + WS_ABUF;
#pragma unroll
      for (int i = 0; i < 8; ++i) {
        float4 o;
        float* op = (float*)&o;
#pragma unroll
        for (int j = 0; j < 4; ++j) {
          float z  = acc[i][j] + bdp[j];
          float sp = (z > 0.0f) ? (z + log1pf(__expf(-z))) : log1pf(__expf(z));
          float dt = fminf(sp, 1.0f);
          dtv[i][j] = dt;
          float la = dt * avp[j];
          la = fmaxf(la, -0.5f);
          la = fminf(la, 0.0f);
          op[j] = __expf(la);
        }
        *(float4*)(aBuf + (long)(bc * CK + t0 + i) * S_ + s0) = o;
      }
    } else if (p == 1) {
      float* uBuf = ws + WS_UBUF;
#pragma unroll
      for (int i = 0; i < 8; ++i) {
        float4 o;
        ((float*)&o)[0] = acc[i][0] * dtv[i][0];
        ((float*)&o)[1] = acc[i][1] * dtv[i][1];
        ((float*)&o)[2] = acc[i][2] * dtv[i][2];
        ((float*)&o)[3] = acc[i][3] * dtv[i][3];
        *(float4*)(uBuf + (long)(bc * CK + t0 + i) * S_ + s0) = o;
      }
    } else {
      float* cBuf = ws + WS_CBUF;
#pragma unroll
      for (int i = 0; i < 8; ++i) {
        float4 o = {acc[i][0], acc[i][1], acc[i][2], acc[i][3]};
        *(float4*)(cBuf + (long)(bc * CK + t0 + i) * S_ + s0) = o;
      }
    }
  }
}

// ---------------- K2: per-chunk local scan ----------------
__global__ __launch_bounds__(128) void k2_scan(float* __restrict__ ws) {
  const int bc = blockIdx.x;
  const int s  = threadIdx.x;
  float* aB = ws + WS_ABUF + (long)bc * CK * S_ + s;
  float* uB = ws + WS_UBUF + (long)bc * CK * S_ + s;
  float h = 0.0f, P = 1.0f;
#pragma unroll 8
  for (int t = 0; t < CK; ++t) {
    float a = aB[t * S_];
    float u = uB[t * S_];
    h = fmaf(a, h, u);
    P *= a;
    aB[t * S_] = P;   // cumP
    uB[t * S_] = h;   // h_local
  }
  ws[WS_CARRYA + bc * S_ + s] = P;
  ws[WS_CARRYH + bc * S_ + s] = h;
}

// ---------------- K3: carry scan over chunks ----------------
__global__ __launch_bounds__(128) void k3_carry(float* __restrict__ ws) {
  const int b = blockIdx.x;
  const int s = threadIdx.x;
  const float* cA = ws + WS_CARRYA;
  const float* cH = ws + WS_CARRYH;
  float* H0 = ws + WS_H0;
  float H = 0.0f;
#pragma unroll 8
  for (int c = 0; c < NC; ++c) {
    int idx = (b * NC + c) * S_ + s;
    H0[idx] = H;                       // state BEFORE chunk c
    H = fmaf(cA[idx], H, cH[idx]);
  }
}

// ---------------- K4: fixup + y + output GEMM + final add ----------------
__global__ __launch_bounds__(256) void k4_out(
    const float* __restrict__ x, float* __restrict__ out,
    float* __restrict__ ws) {
  __shared__ unsigned short hT[128 * 72];  // bf16 [s][t] (stride 72 -> rows 16B aligned)
  __shared__ float wt[64 * 128];           // WoutT slice [s-slice][d]
  __shared__ float yl[64];
  __shared__ float x0l[64];

  const int tid = threadIdx.x;
  const int bc  = blockIdx.x;
  const int sq  = tid & 31, s0 = sq << 2;
  const int tg  = tid >> 5, t0 = tg << 3;

  const float* cp = ws + WS_ABUF + (long)bc * CK * S_;   // cumP
  const float* hl = ws + WS_UBUF + (long)bc * CK * S_;   // h_local
  const float* cb = ws + WS_CBUF + (long)bc * CK * S_;   // C
  float4 h0v = *(const float4*)(ws + WS_H0 + bc * S_ + s0);
  const float* h0p = (const float*)&h0v;

#pragma unroll
  for (int p = 0; p < 8; ++p) {
    int tl = tg + p * 8;
    long off = (long)tl * S_ + s0;
    float4 P4 = *(const float4*)(cp + off);
    float4 L4 = *(const float4*)(hl + off);
    float4 C4 = *(const float4*)(cb + off);
    float hv[4];
    hv[0] = fmaf(P4.x, h0p[0], L4.x);
    hv[1] = fmaf(P4.y, h0p[1], L4.y);
    hv[2] = fmaf(P4.z, h0p[2], L4.z);
    hv[3] = fmaf(P4.w, h0p[3], L4.w);
    float yacc = C4.x * hv[0] + C4.y * hv[1] + C4.z * hv[2] + C4.w * hv[3];
    yacc += __shfl_xor(yacc, 16);
    yacc += __shfl_xor(yacc, 8);
    yacc += __shfl_xor(yacc, 4);
    yacc += __shfl_xor(yacc, 2);
    yacc += __shfl_xor(yacc, 1);
    if (sq == 0) {
      yl[tl]  = yacc;
      x0l[tl] = x[((long)bc * CK + tl) * D_];  // x[b][t][0]
    }
#pragma unroll
    for (int j = 0; j < 4; ++j) {
      __hip_bfloat16 bh = __float2bfloat16(hv[j]);
      hT[(s0 + j) * 72 + tl] = *(unsigned short*)&bh;
    }
  }

  __syncthreads();

  float o[8][4];
#pragma unroll
  for (int i = 0; i < 8; ++i)
#pragma unroll
    for (int j = 0; j < 4; ++j) o[i][j] = 0.0f;

  const float* WoutT = ws + WS_WOUTT;   // [s][d]
  for (int ks = 0; ks < 2; ++ks) {
    if (ks) __syncthreads();
    const float4* wsrc = (const float4*)(WoutT + ks * 64 * 128);
#pragma unroll
    for (int i = 0; i < 8; ++i)
      ((float4*)wt)[tid + 256 * i] = wsrc[tid + 256 * i];
    __syncthreads();

    for (int k = 0; k < 64; ++k) {
      int s = ks * 64 + k;
      float4 w4 = ((const float4*)wt)[k * 32 + sq];   // WoutT[s][d0..d0+3]
      const float* wv = (const float*)&w4;
      uint4 hx = *(const uint4*)&hT[s * 72 + t0];     // 8 bf16 (t0..t0+7)
      float ht[8];
      ht[0] = __uint_as_float(hx.x << 16);
      ht[1] = __uint_as_float(hx.x & 0xFFFF0000u);
      ht[2] = __uint_as_float(hx.y << 16);
      ht[3] = __uint_as_float(hx.y & 0xFFFF0000u);
      ht[4] = __uint_as_float(hx.z << 16);
      ht[5] = __uint_as_float(hx.z & 0xFFFF0000u);
      ht[6] = __uint_as_float(hx.w << 16);
      ht[7] = __uint_as_float(hx.w & 0xFFFF0000u);
#pragma unroll
      for (int i = 0; i < 8; ++i)
#pragma unroll
        for (int j = 0; j < 4; ++j)
          o[i][j] = fmaf(ht[i], wv[j], o[i][j]);
    }
  }

#pragma unroll
  for (int i = 0; i < 8; ++i) {
    int tl = t0 + i;
    float yx = yl[tl] * x0l[tl];
    float4 v = {o[i][0] + yx, o[i][1] + yx, o[i][2] + yx, o[i][3] + yx};
    *(float4*)(out + ((long)bc * CK + tl) * D_ + s0) = v;   // d index = s0 here
  }
}

extern "C" void kernel_launch(void* const* d_in, const int* in_sizes, int n_in,
                              void* d_out, int out_size, void* d_ws, size_t ws_size,
                              hipStream_t stream) {
  const float* x    = (const float*)d_in[0];
  const float* logA = (const float*)d_in[1];
  const float* W_B  = (const float*)d_in[2];
  const float* W_C  = (const float*)d_in[3];
  const float* W_dt = (const float*)d_in[4];
  const float* b_dt = (const float*)d_in[5];
  const float* W_out= (const float*)d_in[6];
  float* out = (float*)d_out;
  float* ws  = (float*)d_ws;

  k0_prep<<<4, 256, 0, stream>>>(W_dt, W_B, W_C, W_out, logA, ws);
  k1_proj<<<NCHUNK, 256, 0, stream>>>(x, b_dt, ws);
  k2_scan<<<NCHUNK, 128, 0, stream>>>(ws);
  k3_carry<<<B_, 128, 0, stream>>>(ws);
  k4_out<<<NCHUNK, 256, 0, stream>>>(x, out, ws);
}

// Round 2
// 200.917 us; speedup vs baseline: 1.4463x; 1.4463x over previous
//
#include <hip/hip_runtime.h>
#include <hip/hip_bf16.h>

// Problem constants
#define B_ 8
#define T_ 8192
#define D_ 128
#define S_ 128
#define CK 64
#define NC 128           // T_/CK
#define NCHUNK (B_*NC)   // 1024

typedef __attribute__((ext_vector_type(8))) __bf16 bf16x8;
typedef __attribute__((ext_vector_type(4))) float floatx4;

// ws layout (in floats)
// bf16 weights: Wdt, WB, WC in [s][d]; Wout in [d][s]  (all as-given, just converted)
#define WS_WBF     0                       // 4*16384 bf16 = 32768 floats of storage
#define WS_AVEC    32768                   // 128
#define WS_ABUF    32896                   // B*T*S : cumP
#define WS_UBUF    (WS_ABUF + 8388608)     // B*T*S : h_local
#define WS_CBUF    (WS_UBUF + 8388608)     // B*T*S : C
#define WS_CARRYA  (WS_CBUF + 8388608)     // B*NC*S
#define WS_CARRYH  (WS_CARRYA + 131072)
#define WS_H0      (WS_CARRYH + 131072)
// total ~25.6M floats (~102 MB)

__device__ __forceinline__ unsigned short f2bf(float f) {
  __hip_bfloat16 b = __float2bfloat16(f);
  return *(unsigned short*)&b;
}

// ---------------- K0: convert weights to bf16, precompute A ----------------
__global__ __launch_bounds__(256) void k0_prep(
    const float* __restrict__ Wdt, const float* __restrict__ WB,
    const float* __restrict__ WC,  const float* __restrict__ Wout,
    const float* __restrict__ logA, float* __restrict__ ws) {
  unsigned short* wb = (unsigned short*)(ws + WS_WBF);
  int gid = blockIdx.x * 256 + threadIdx.x;   // 0..4095
  const float* srcs[4] = {Wdt, WB, WC, Wout};
#pragma unroll
  for (int i = 0; i < 16; ++i) {
    int f = gid + 4096 * i;                   // 0..65535
    int m = f >> 14, r = f & 16383;
    wb[f] = f2bf(srcs[m][r]);
  }
  if (blockIdx.x == 0 && threadIdx.x < 128)
    ws[WS_AVEC + threadIdx.x] = -fminf(expf(logA[threadIdx.x]), 10.0f);
}

// ---------------- K1: MFMA projections + fused chunk scan ----------------
// block = 1 chunk (64 t) x 128 s, 4 waves; wave w owns t-rows [16w,16w+16)
__global__ __launch_bounds__(256) void k1_proj(
    const float* __restrict__ x, const float* __restrict__ bdt,
    float* __restrict__ ws) {
  __shared__ __align__(16) unsigned short xb[64 * 136];  // bf16 [t][d], pad 8
  __shared__ float wlsP[4 * 128];
  __shared__ float wlsH[4 * 128];

  const int tid  = threadIdx.x;
  const int bc   = blockIdx.x;
  const int w    = tid >> 6;
  const int lane = tid & 63;
  const int g    = lane >> 4;
  const int c    = lane & 15;

  // ---- stage x tile fp32 -> bf16 LDS [t][136] ----
  const float4* x4 = (const float4*)(x + (long)bc * CK * D_);
#pragma unroll
  for (int i = 0; i < 8; ++i) {
    int f4 = tid + 256 * i;     // 2048 float4
    int t  = f4 >> 5;
    int d0 = (f4 & 31) << 2;
    float4 v = x4[f4];
    ushort4 o;
    o.x = f2bf(v.x); o.y = f2bf(v.y); o.z = f2bf(v.z); o.w = f2bf(v.w);
    *(ushort4*)&xb[t * 136 + d0] = o;
  }
  __syncthreads();

  // ---- A fragments: row m = 16w + c, k0 = 8g + 32kk ----
  bf16x8 afr[4];
#pragma unroll
  for (int kk = 0; kk < 4; ++kk)
    afr[kk] = *(const bf16x8*)&xb[(16 * w + c) * 136 + 8 * g + 32 * kk];

  const unsigned short* wb = (const unsigned short*)(ws + WS_WBF);

  float dtacc[8][4], bacc[8][4];

  // ---- GEMM dt and B (B-frags streamed from global, layout [s][d]) ----
#pragma unroll
  for (int nt = 0; nt < 8; ++nt) {
    floatx4 a4 = {0.f, 0.f, 0.f, 0.f};
#pragma unroll
    for (int kk = 0; kk < 4; ++kk) {
      bf16x8 bfr = *(const bf16x8*)&wb[(16 * nt + c) * 128 + 8 * g + 32 * kk];
      a4 = __builtin_amdgcn_mfma_f32_16x16x32_bf16(afr[kk], bfr, a4, 0, 0, 0);
    }
    dtacc[nt][0] = a4.x; dtacc[nt][1] = a4.y; dtacc[nt][2] = a4.z; dtacc[nt][3] = a4.w;
  }
#pragma unroll
  for (int nt = 0; nt < 8; ++nt) {
    floatx4 a4 = {0.f, 0.f, 0.f, 0.f};
#pragma unroll
    for (int kk = 0; kk < 4; ++kk) {
      bf16x8 bfr = *(const bf16x8*)&wb[16384 + (16 * nt + c) * 128 + 8 * g + 32 * kk];
      a4 = __builtin_amdgcn_mfma_f32_16x16x32_bf16(afr[kk], bfr, a4, 0, 0, 0);
    }
    bacc[nt][0] = a4.x; bacc[nt][1] = a4.y; bacc[nt][2] = a4.z; bacc[nt][3] = a4.w;
  }

  // ---- elementwise: dt, a, u  (col s = 16nt + c, row t = 16w + 4g + i) ----
  float Av[8], Bd[8];
#pragma unroll
  for (int nt = 0; nt < 8; ++nt) {
    Av[nt] = ws[WS_AVEC + 16 * nt + c];
    Bd[nt] = bdt[16 * nt + c];
  }
#pragma unroll
  for (int nt = 0; nt < 8; ++nt)
#pragma unroll
    for (int i = 0; i < 4; ++i) {
      float z  = dtacc[nt][i] + Bd[nt];
      float sp = (z > 0.0f) ? (z + log1pf(__expf(-z))) : log1pf(__expf(z));
      float dt = fminf(sp, 1.0f);
      float u  = bacc[nt][i] * dt;
      float la = fmaxf(fminf(dt * Av[nt], 0.0f), -0.5f);
      dtacc[nt][i] = __expf(la);   // a
      bacc[nt][i]  = u;            // u
    }

  // ---- hierarchical inclusive scan over t (within chunk) ----
  // intra-lane: rows 4g..4g+3
#pragma unroll
  for (int nt = 0; nt < 8; ++nt) {
    float P = dtacc[nt][0], H = bacc[nt][0];
#pragma unroll
    for (int i = 1; i < 4; ++i) {
      H = fmaf(H, dtacc[nt][i], bacc[nt][i]);
      P = P * dtacc[nt][i];
      dtacc[nt][i] = P;   // intra-lane prefix product Pp
      bacc[nt][i]  = H;   // intra-lane prefix scan Hp
    }
  }
  // inter-segment (g) Kogge-Stone + exclusive, per nt
#pragma unroll
  for (int nt = 0; nt < 8; ++nt) {
    float P = dtacc[nt][3], H = bacc[nt][3];
    float Po = __shfl(P, (lane - 16) & 63), Ho = __shfl(H, (lane - 16) & 63);
    if (g >= 1) { H = fmaf(Ho, P, H); P = Po * P; }
    Po = __shfl(P, (lane - 32) & 63); Ho = __shfl(H, (lane - 32) & 63);
    if (g >= 2) { H = fmaf(Ho, P, H); P = Po * P; }
    float Pe = __shfl(P, (lane - 16) & 63), He = __shfl(H, (lane - 16) & 63);
    if (g == 0) { Pe = 1.0f; He = 0.0f; }
#pragma unroll
    for (int i = 0; i < 4; ++i) {
      bacc[nt][i] = fmaf(dtacc[nt][i], He, bacc[nt][i]);  // Hw (wave-local incl)
      dtacc[nt][i] = dtacc[nt][i] * Pe;                   // Pw
    }
    if (g == 3) {
      wlsP[w * 128 + 16 * nt + c] = dtacc[nt][3];
      wlsH[w * 128 + 16 * nt + c] = bacc[nt][3];
    }
  }
  __syncthreads();
  // inter-wave exclusive prefix
#pragma unroll
  for (int nt = 0; nt < 8; ++nt) {
    float Pe = 1.0f, He = 0.0f;
    for (int ww = 0; ww < 3; ++ww) {
      if (ww < w) {
        float Pw_ = wlsP[ww * 128 + 16 * nt + c];
        float Hw_ = wlsH[ww * 128 + 16 * nt + c];
        He = fmaf(He, Pw_, Hw_);
        Pe = Pe * Pw_;
      }
    }
#pragma unroll
    for (int i = 0; i < 4; ++i) {
      bacc[nt][i] = fmaf(dtacc[nt][i], He, bacc[nt][i]);  // chunk-incl h_local
      dtacc[nt][i] = dtacc[nt][i] * Pe;                   // chunk-incl cumP
    }
  }

  // ---- chunk carries ----
  if (w == 3 && g == 3) {
#pragma unroll
    for (int nt = 0; nt < 8; ++nt) {
      ws[WS_CARRYA + bc * 128 + 16 * nt + c] = dtacc[nt][3];
      ws[WS_CARRYH + bc * 128 + 16 * nt + c] = bacc[nt][3];
    }
  }

  // ---- write cumP / h_local ----
  float* aB = ws + WS_ABUF + (long)bc * CK * S_;
  float* uB = ws + WS_UBUF + (long)bc * CK * S_;
#pragma unroll
  for (int nt = 0; nt < 8; ++nt)
#pragma unroll
    for (int i = 0; i < 4; ++i) {
      int row = 16 * w + 4 * g + i, col = 16 * nt + c;
      aB[row * 128 + col] = dtacc[nt][i];
      uB[row * 128 + col] = bacc[nt][i];
    }

  // ---- GEMM C and write ----
  float* cB = ws + WS_CBUF + (long)bc * CK * S_;
#pragma unroll
  for (int nt = 0; nt < 8; ++nt) {
    floatx4 a4 = {0.f, 0.f, 0.f, 0.f};
#pragma unroll
    for (int kk = 0; kk < 4; ++kk) {
      bf16x8 bfr = *(const bf16x8*)&wb[2 * 16384 + (16 * nt + c) * 128 + 8 * g + 32 * kk];
      a4 = __builtin_amdgcn_mfma_f32_16x16x32_bf16(afr[kk], bfr, a4, 0, 0, 0);
    }
#pragma unroll
    for (int i = 0; i < 4; ++i)
      cB[(16 * w + 4 * g + i) * 128 + 16 * nt + c] = a4[i];
  }
}

// ---------------- K3: carry scan over chunks (batched prefetch) ----------------
__global__ __launch_bounds__(128) void k3_carry(float* __restrict__ ws) {
  const int b = blockIdx.x;
  const int s = threadIdx.x;
  const float* cA = ws + WS_CARRYA + b * NC * S_ + s;
  const float* cH = ws + WS_CARRYH + b * NC * S_ + s;
  float* H0 = ws + WS_H0 + b * NC * S_ + s;
  float H = 0.0f;
  float pa[16], ph[16];
#pragma unroll
  for (int j = 0; j < 16; ++j) { pa[j] = cA[j * S_]; ph[j] = cH[j * S_]; }
  for (int cb = 0; cb < 8; ++cb) {
    float na[16], nh[16];
    if (cb < 7) {
#pragma unroll
      for (int j = 0; j < 16; ++j) {
        na[j] = cA[(cb * 16 + 16 + j) * S_];
        nh[j] = cH[(cb * 16 + 16 + j) * S_];
      }
    }
#pragma unroll
    for (int j = 0; j < 16; ++j) {
      H0[(cb * 16 + j) * S_] = H;
      H = fmaf(pa[j], H, ph[j]);
    }
#pragma unroll
    for (int j = 0; j < 16; ++j) { pa[j] = na[j]; ph[j] = nh[j]; }
  }
}

// ---------------- K4: fixup + y + MFMA out-GEMM + final add ----------------
__global__ __launch_bounds__(256) void k4_out(
    const float* __restrict__ x, float* __restrict__ out,
    float* __restrict__ ws) {
  __shared__ __align__(16) unsigned short hT[64 * 136];  // bf16 [t][s] pad 8
  __shared__ float yx[64];

  const int tid = threadIdx.x;
  const int bc  = blockIdx.x;
  const int sq  = tid & 31, s0 = sq << 2;
  const int tg  = tid >> 5;

  const float* cp = ws + WS_ABUF + (long)bc * CK * S_;
  const float* hl = ws + WS_UBUF + (long)bc * CK * S_;
  const float* cb = ws + WS_CBUF + (long)bc * CK * S_;
  float4 h0v = *(const float4*)(ws + WS_H0 + bc * S_ + s0);
  const float* h0p = (const float*)&h0v;

#pragma unroll
  for (int p = 0; p < 8; ++p) {
    int tl = tg + p * 8;
    long off = (long)tl * S_ + s0;
    float4 P4 = *(const float4*)(cp + off);
    float4 L4 = *(const float4*)(hl + off);
    float4 C4 = *(const float4*)(cb + off);
    float hv[4];
    hv[0] = fmaf(P4.x, h0p[0], L4.x);
    hv[1] = fmaf(P4.y, h0p[1], L4.y);
    hv[2] = fmaf(P4.z, h0p[2], L4.z);
    hv[3] = fmaf(P4.w, h0p[3], L4.w);
    float yacc = C4.x * hv[0] + C4.y * hv[1] + C4.z * hv[2] + C4.w * hv[3];
    yacc += __shfl_xor(yacc, 16);
    yacc += __shfl_xor(yacc, 8);
    yacc += __shfl_xor(yacc, 4);
    yacc += __shfl_xor(yacc, 2);
    yacc += __shfl_xor(yacc, 1);
    if (sq == 0) yx[tl] = yacc * x[((long)bc * CK + tl) * D_];
    ushort4 o;
    o.x = f2bf(hv[0]); o.y = f2bf(hv[1]); o.z = f2bf(hv[2]); o.w = f2bf(hv[3]);
    *(ushort4*)&hT[tl * 136 + s0] = o;
  }
  __syncthreads();

  // out[t][d] = sum_s h[t][s] * Wout[d][s] ; B-operand = Wout bf16 [d][s]
  const int w    = tid >> 6;
  const int lane = tid & 63;
  const int g    = lane >> 4;
  const int c    = lane & 15;

  bf16x8 afr[4];
#pragma unroll
  for (int kk = 0; kk < 4; ++kk)
    afr[kk] = *(const bf16x8*)&hT[(16 * w + c) * 136 + 8 * g + 32 * kk];

  const unsigned short* wo = (const unsigned short*)(ws + WS_WBF) + 3 * 16384;
#pragma unroll
  for (int nt = 0; nt < 8; ++nt) {
    floatx4 a4 = {0.f, 0.f, 0.f, 0.f};
#pragma unroll
    for (int kk = 0; kk < 4; ++kk) {
      bf16x8 bfr = *(const bf16x8*)&wo[(16 * nt + c) * 128 + 8 * g + 32 * kk];
      a4 = __builtin_amdgcn_mfma_f32_16x16x32_bf16(afr[kk], bfr, a4, 0, 0, 0);
    }
#pragma unroll
    for (int i = 0; i < 4; ++i) {
      int row = 16 * w + 4 * g + i;
      out[((long)bc * CK + row) * D_ + 16 * nt + c] = a4[i] + yx[row];
    }
  }
}

extern "C" void kernel_launch(void* const* d_in, const int* in_sizes, int n_in,
                              void* d_out, int out_size, void* d_ws, size_t ws_size,
                              hipStream_t stream) {
  const float* x    = (const float*)d_in[0];
  const float* logA = (const float*)d_in[1];
  const float* W_B  = (const float*)d_in[2];
  const float* W_C  = (const float*)d_in[3];
  const float* W_dt = (const float*)d_in[4];
  const float* b_dt = (const float*)d_in[5];
  const float* W_out= (const float*)d_in[6];
  float* out = (float*)d_out;
  float* ws  = (float*)d_ws;

  k0_prep<<<16, 256, 0, stream>>>(W_dt, W_B, W_C, W_out, logA, ws);
  k1_proj<<<NCHUNK, 256, 0, stream>>>(x, b_dt, ws);
  k3_carry<<<B_, 128, 0, stream>>>(ws);
  k4_out<<<NCHUNK, 256, 0, stream>>>(x, out, ws);
}

// Round 3
// 198.797 us; speedup vs baseline: 1.4617x; 1.0107x over previous
//
#include <hip/hip_runtime.h>
#include <hip/hip_bf16.h>

// Problem constants
#define B_ 8
#define T_ 8192
#define D_ 128
#define S_ 128
#define CK 64
#define NC 128           // T_/CK
#define NCHUNK (B_*NC)   // 1024

typedef __attribute__((ext_vector_type(8))) __bf16 bf16x8;
typedef __attribute__((ext_vector_type(4))) float floatx4;

// ws layout (floats). Only weights + carries now (~1.7 MB).
#define WS_WBF     0                        // 4 mats bf16 = 65536 ushort = 32768 floats
#define WS_AVEC    32768                    // 128
#define WS_CARRYA  32896                    // NCHUNK*128
#define WS_CARRYH  (WS_CARRYA + 131072)
#define WS_H0      (WS_CARRYH + 131072)

__device__ __forceinline__ unsigned short f2bf(float f) {
  __hip_bfloat16 b = __float2bfloat16(f);
  return *(unsigned short*)&b;
}

__device__ __forceinline__ float softplus1(float z) {
  // min(softplus(z), 1)
  float sp = fmaxf(z, 0.0f) + __logf(1.0f + __expf(-fabsf(z)));
  return fminf(sp, 1.0f);
}

// ---------------- K0: weights -> bf16, precompute A ----------------
__global__ __launch_bounds__(256) void k0_prep(
    const float* __restrict__ Wdt, const float* __restrict__ WB,
    const float* __restrict__ WC,  const float* __restrict__ Wout,
    const float* __restrict__ logA, float* __restrict__ ws) {
  unsigned short* wb = (unsigned short*)(ws + WS_WBF);
  int gid = blockIdx.x * 256 + threadIdx.x;   // 0..4095
  const float* srcs[4] = {Wdt, WB, WC, Wout};
#pragma unroll
  for (int i = 0; i < 16; ++i) {
    int f = gid + 4096 * i;                   // 0..65535
    int m = f >> 14, r = f & 16383;
    wb[f] = f2bf(srcs[m][r]);
  }
  if (blockIdx.x == 0 && threadIdx.x < 128)
    ws[WS_AVEC + threadIdx.x] = -fminf(expf(logA[threadIdx.x]), 10.0f);
}

// fragment load macro: mat in {0:Wdt,1:WB,2:WC,3:Wout}, all [n][k] bf16
#define WFRAG(mat, nt, kk) \
  (*(const bf16x8*)&wb[(mat) * 16384 + (16 * (nt) + c) * 128 + 8 * g + 32 * (kk)])

// ---------------- K1: carry-only kernel ----------------
// block = 1 chunk (64 t), 4 waves; wave w owns rows [16w, 16w+16)
__global__ __launch_bounds__(256, 2) void k1_carry(
    const float* __restrict__ x, const float* __restrict__ bdt,
    float* __restrict__ ws) {
  __shared__ __align__(16) unsigned short xb[64 * 136];  // bf16 [t][d] pad 8
  __shared__ float wlsP[4 * 128];
  __shared__ float wlsH[4 * 128];

  const int tid  = threadIdx.x;
  const int bc   = blockIdx.x;
  const int w    = tid >> 6;
  const int lane = tid & 63;
  const int g    = lane >> 4;
  const int c    = lane & 15;

  // early broadcast loads
  float Av[8], Bd[8];
#pragma unroll
  for (int nt = 0; nt < 8; ++nt) {
    Av[nt] = ws[WS_AVEC + 16 * nt + c];
    Bd[nt] = bdt[16 * nt + c];
  }

  // stage x tile fp32 -> bf16 LDS
  const float4* x4 = (const float4*)(x + (long)bc * CK * D_);
#pragma unroll
  for (int i = 0; i < 8; ++i) {
    int f4 = tid + 256 * i;
    int t  = f4 >> 5;
    int d0 = (f4 & 31) << 2;
    float4 v = x4[f4];
    ushort4 o;
    o.x = f2bf(v.x); o.y = f2bf(v.y); o.z = f2bf(v.z); o.w = f2bf(v.w);
    *(ushort4*)&xb[t * 136 + d0] = o;
  }
  __syncthreads();

  bf16x8 afr[4];
#pragma unroll
  for (int kk = 0; kk < 4; ++kk)
    afr[kk] = *(const bf16x8*)&xb[(16 * w + c) * 136 + 8 * g + 32 * kk];

  const unsigned short* wb = (const unsigned short*)(ws + WS_WBF);

  floatx4 dtacc[8], bacc[8];
#pragma unroll
  for (int nt = 0; nt < 8; ++nt) {
    dtacc[nt] = (floatx4){0.f, 0.f, 0.f, 0.f};
    bacc[nt]  = (floatx4){0.f, 0.f, 0.f, 0.f};
  }

  // dt + B GEMMs, kk-outer with 1-step lookahead
  bf16x8 fD[8], fB[8];
#pragma unroll
  for (int nt = 0; nt < 8; ++nt) fD[nt] = WFRAG(0, nt, 0);
#pragma unroll
  for (int nt = 0; nt < 8; ++nt) fB[nt] = WFRAG(1, nt, 0);
#pragma unroll
  for (int kk = 0; kk < 4; ++kk) {
    bf16x8 nD[8], nB[8];
    if (kk < 3) {
#pragma unroll
      for (int nt = 0; nt < 8; ++nt) nD[nt] = WFRAG(0, nt, kk + 1);
#pragma unroll
      for (int nt = 0; nt < 8; ++nt) nB[nt] = WFRAG(1, nt, kk + 1);
    }
#pragma unroll
    for (int nt = 0; nt < 8; ++nt) {
      dtacc[nt] = __builtin_amdgcn_mfma_f32_16x16x32_bf16(afr[kk], fD[nt], dtacc[nt], 0, 0, 0);
      bacc[nt]  = __builtin_amdgcn_mfma_f32_16x16x32_bf16(afr[kk], fB[nt], bacc[nt], 0, 0, 0);
    }
    if (kk < 3) {
#pragma unroll
      for (int nt = 0; nt < 8; ++nt) { fD[nt] = nD[nt]; fB[nt] = nB[nt]; }
    }
  }

  // fused elementwise + intra-lane running (P,H); only segment totals kept
  float P[8], H[8];
#pragma unroll
  for (int nt = 0; nt < 8; ++nt) {
    float Pl = 1.0f, Hl = 0.0f;
#pragma unroll
    for (int i = 0; i < 4; ++i) {
      float dt = softplus1(dtacc[nt][i] + Bd[nt]);
      float u  = bacc[nt][i] * dt;
      float la = fmaxf(fminf(dt * Av[nt], 0.0f), -0.5f);
      float a  = __expf(la);
      Hl = fmaf(a, Hl, u);
      Pl = Pl * a;
    }
    P[nt] = Pl; H[nt] = Hl;
  }

  // Kogge-Stone over the 4 lane-groups (inclusive)
#pragma unroll
  for (int nt = 0; nt < 8; ++nt) {
    float Po = __shfl(P[nt], (lane - 16) & 63), Ho = __shfl(H[nt], (lane - 16) & 63);
    if (g >= 1) { H[nt] = fmaf(Ho, P[nt], H[nt]); P[nt] = Po * P[nt]; }
    Po = __shfl(P[nt], (lane - 32) & 63); Ho = __shfl(H[nt], (lane - 32) & 63);
    if (g >= 2) { H[nt] = fmaf(Ho, P[nt], H[nt]); P[nt] = Po * P[nt]; }
    if (g == 3) {
      wlsP[w * 128 + 16 * nt + c] = P[nt];
      wlsH[w * 128 + 16 * nt + c] = H[nt];
    }
  }
  __syncthreads();

  // wave 3 combines waves 0..2 and stores chunk carries
  if (w == 3 && g == 3) {
#pragma unroll
    for (int nt = 0; nt < 8; ++nt) {
      float Pe = 1.0f, He = 0.0f;
#pragma unroll
      for (int ww = 0; ww < 3; ++ww) {
        float Pw = wlsP[ww * 128 + 16 * nt + c];
        float Hw = wlsH[ww * 128 + 16 * nt + c];
        He = fmaf(He, Pw, Hw);
        Pe = Pe * Pw;
      }
      ws[WS_CARRYA + bc * 128 + 16 * nt + c] = P[nt] * Pe;
      ws[WS_CARRYH + bc * 128 + 16 * nt + c] = fmaf(P[nt], He, H[nt]);
    }
  }
}

// ---------------- K3: carry scan over chunks ----------------
__global__ __launch_bounds__(128) void k3_carry(float* __restrict__ ws) {
  const int b = blockIdx.x;
  const int s = threadIdx.x;
  const float* cA = ws + WS_CARRYA + b * NC * S_ + s;
  const float* cH = ws + WS_CARRYH + b * NC * S_ + s;
  float* H0 = ws + WS_H0 + b * NC * S_ + s;
  float H = 0.0f;
  float pa[16], ph[16];
#pragma unroll
  for (int j = 0; j < 16; ++j) { pa[j] = cA[j * S_]; ph[j] = cH[j * S_]; }
  for (int cb = 0; cb < 8; ++cb) {
    float na[16], nh[16];
    if (cb < 7) {
#pragma unroll
      for (int j = 0; j < 16; ++j) {
        na[j] = cA[(cb * 16 + 16 + j) * S_];
        nh[j] = cH[(cb * 16 + 16 + j) * S_];
      }
    }
#pragma unroll
    for (int j = 0; j < 16; ++j) {
      H0[(cb * 16 + j) * S_] = H;
      H = fmaf(pa[j], H, ph[j]);
    }
#pragma unroll
    for (int j = 0; j < 16; ++j) { pa[j] = na[j]; ph[j] = nh[j]; }
  }
}

// ---------------- K4: recompute + scan + fixup + y + out GEMM ----------------
__global__ __launch_bounds__(256, 2) void k4_main(
    const float* __restrict__ x, const float* __restrict__ bdt,
    float* __restrict__ out, float* __restrict__ ws) {
  __shared__ __align__(16) unsigned short xb[64 * 136];  // x bf16, reused as hT
  __shared__ float wlsP[4 * 128];
  __shared__ float wlsH[4 * 128];
  __shared__ float yx[64];

  const int tid  = threadIdx.x;
  const int bc   = blockIdx.x;
  const int w    = tid >> 6;
  const int lane = tid & 63;
  const int g    = lane >> 4;
  const int c    = lane & 15;

  float Av[8], Bd[8], h0[8];
#pragma unroll
  for (int nt = 0; nt < 8; ++nt) {
    Av[nt] = ws[WS_AVEC + 16 * nt + c];
    Bd[nt] = bdt[16 * nt + c];
    h0[nt] = ws[WS_H0 + bc * 128 + 16 * nt + c];
  }
  float x0[4];
  if (c == 0) {
#pragma unroll
    for (int i = 0; i < 4; ++i)
      x0[i] = x[((long)bc * CK + 16 * w + 4 * g + i) * D_];
  }

  const float4* x4 = (const float4*)(x + (long)bc * CK * D_);
#pragma unroll
  for (int i = 0; i < 8; ++i) {
    int f4 = tid + 256 * i;
    int t  = f4 >> 5;
    int d0 = (f4 & 31) << 2;
    float4 v = x4[f4];
    ushort4 o;
    o.x = f2bf(v.x); o.y = f2bf(v.y); o.z = f2bf(v.z); o.w = f2bf(v.w);
    *(ushort4*)&xb[t * 136 + d0] = o;
  }
  __syncthreads();

  bf16x8 afr[4];
#pragma unroll
  for (int kk = 0; kk < 4; ++kk)
    afr[kk] = *(const bf16x8*)&xb[(16 * w + c) * 136 + 8 * g + 32 * kk];

  const unsigned short* wb = (const unsigned short*)(ws + WS_WBF);

  floatx4 dtacc[8], bacc[8];
#pragma unroll
  for (int nt = 0; nt < 8; ++nt) {
    dtacc[nt] = (floatx4){0.f, 0.f, 0.f, 0.f};
    bacc[nt]  = (floatx4){0.f, 0.f, 0.f, 0.f};
  }

  {  // dt + B GEMMs with lookahead
    bf16x8 fD[8], fB[8];
#pragma unroll
    for (int nt = 0; nt < 8; ++nt) fD[nt] = WFRAG(0, nt, 0);
#pragma unroll
    for (int nt = 0; nt < 8; ++nt) fB[nt] = WFRAG(1, nt, 0);
#pragma unroll
    for (int kk = 0; kk < 4; ++kk) {
      bf16x8 nD[8], nB[8];
      if (kk < 3) {
#pragma unroll
        for (int nt = 0; nt < 8; ++nt) nD[nt] = WFRAG(0, nt, kk + 1);
#pragma unroll
        for (int nt = 0; nt < 8; ++nt) nB[nt] = WFRAG(1, nt, kk + 1);
      }
#pragma unroll
      for (int nt = 0; nt < 8; ++nt) {
        dtacc[nt] = __builtin_amdgcn_mfma_f32_16x16x32_bf16(afr[kk], fD[nt], dtacc[nt], 0, 0, 0);
        bacc[nt]  = __builtin_amdgcn_mfma_f32_16x16x32_bf16(afr[kk], fB[nt], bacc[nt], 0, 0, 0);
      }
      if (kk < 3) {
#pragma unroll
        for (int nt = 0; nt < 8; ++nt) { fD[nt] = nD[nt]; fB[nt] = nB[nt]; }
      }
    }
  }

  // prefetch C fragments kk=0, then elementwise -> a (dtacc), u (bacc)
  bf16x8 fC[8];
#pragma unroll
  for (int nt = 0; nt < 8; ++nt) fC[nt] = WFRAG(2, nt, 0);

#pragma unroll
  for (int nt = 0; nt < 8; ++nt)
#pragma unroll
    for (int i = 0; i < 4; ++i) {
      float dt = softplus1(dtacc[nt][i] + Bd[nt]);
      float u  = bacc[nt][i] * dt;
      float la = fmaxf(fminf(dt * Av[nt], 0.0f), -0.5f);
      dtacc[nt][i] = __expf(la);   // a
      bacc[nt][i]  = u;            // u
    }

  // C GEMM with lookahead
  floatx4 cacc[8];
#pragma unroll
  for (int nt = 0; nt < 8; ++nt) cacc[nt] = (floatx4){0.f, 0.f, 0.f, 0.f};
#pragma unroll
  for (int kk = 0; kk < 4; ++kk) {
    bf16x8 nC[8];
    if (kk < 3) {
#pragma unroll
      for (int nt = 0; nt < 8; ++nt) nC[nt] = WFRAG(2, nt, kk + 1);
    }
#pragma unroll
    for (int nt = 0; nt < 8; ++nt)
      cacc[nt] = __builtin_amdgcn_mfma_f32_16x16x32_bf16(afr[kk], fC[nt], cacc[nt], 0, 0, 0);
    if (kk < 3) {
#pragma unroll
      for (int nt = 0; nt < 8; ++nt) fC[nt] = nC[nt];
    }
  }

  // ---- hierarchical scan (full prefixes; verified in R2) ----
#pragma unroll
  for (int nt = 0; nt < 8; ++nt) {
    float P = dtacc[nt][0], H = bacc[nt][0];
#pragma unroll
    for (int i = 1; i < 4; ++i) {
      H = fmaf(H, dtacc[nt][i], bacc[nt][i]);
      P = P * dtacc[nt][i];
      dtacc[nt][i] = P;
      bacc[nt][i]  = H;
    }
  }
#pragma unroll
  for (int nt = 0; nt < 8; ++nt) {
    float P = dtacc[nt][3], H = bacc[nt][3];
    float Po = __shfl(P, (lane - 16) & 63), Ho = __shfl(H, (lane - 16) & 63);
    if (g >= 1) { H = fmaf(Ho, P, H); P = Po * P; }
    Po = __shfl(P, (lane - 32) & 63); Ho = __shfl(H, (lane - 32) & 63);
    if (g >= 2) { H = fmaf(Ho, P, H); P = Po * P; }
    float Pe = __shfl(P, (lane - 16) & 63), He = __shfl(H, (lane - 16) & 63);
    if (g == 0) { Pe = 1.0f; He = 0.0f; }
#pragma unroll
    for (int i = 0; i < 4; ++i) {
      bacc[nt][i] = fmaf(dtacc[nt][i], He, bacc[nt][i]);
      dtacc[nt][i] = dtacc[nt][i] * Pe;
    }
    if (g == 3) {
      wlsP[w * 128 + 16 * nt + c] = dtacc[nt][3];
      wlsH[w * 128 + 16 * nt + c] = bacc[nt][3];
    }
  }
  __syncthreads();
#pragma unroll
  for (int nt = 0; nt < 8; ++nt) {
    float Pe = 1.0f, He = 0.0f;
    for (int ww = 0; ww < 3; ++ww) {
      if (ww < w) {
        float Pw = wlsP[ww * 128 + 16 * nt + c];
        float Hw = wlsH[ww * 128 + 16 * nt + c];
        He = fmaf(He, Pw, Hw);
        Pe = Pe * Pw;
      }
    }
#pragma unroll
    for (int i = 0; i < 4; ++i) {
      bacc[nt][i] = fmaf(dtacc[nt][i], He, bacc[nt][i]);   // h_local (chunk-incl)
      dtacc[nt][i] = dtacc[nt][i] * Pe;                    // cumP (chunk-incl)
    }
  }

  // ---- fixup h = h_local + cumP*H0, y, hT ----
  float yv[4] = {0.f, 0.f, 0.f, 0.f};
  unsigned short* hT = xb;   // safe: xb reads (afr) happened before wls barrier
#pragma unroll
  for (int nt = 0; nt < 8; ++nt)
#pragma unroll
    for (int i = 0; i < 4; ++i) {
      float hv = fmaf(dtacc[nt][i], h0[nt], bacc[nt][i]);
      yv[i] = fmaf(cacc[nt][i], hv, yv[i]);
      hT[(16 * w + 4 * g + i) * 136 + 16 * nt + c] = f2bf(hv);
    }
#pragma unroll
  for (int i = 0; i < 4; ++i) {
    yv[i] += __shfl_xor(yv[i], 1);
    yv[i] += __shfl_xor(yv[i], 2);
    yv[i] += __shfl_xor(yv[i], 4);
    yv[i] += __shfl_xor(yv[i], 8);
  }
  if (c == 0) {
#pragma unroll
    for (int i = 0; i < 4; ++i) yx[16 * w + 4 * g + i] = yv[i] * x0[i];
  }

  // prefetch Wout frags kk=0 before the barrier
  bf16x8 fO[8];
#pragma unroll
  for (int nt = 0; nt < 8; ++nt) fO[nt] = WFRAG(3, nt, 0);
  __syncthreads();

  // ---- out GEMM: A = h bf16 [t][s], B = Wout [d][s] ----
  bf16x8 hfr[4];
#pragma unroll
  for (int kk = 0; kk < 4; ++kk)
    hfr[kk] = *(const bf16x8*)&hT[(16 * w + c) * 136 + 8 * g + 32 * kk];

  floatx4 oacc[8];
#pragma unroll
  for (int nt = 0; nt < 8; ++nt) oacc[nt] = (floatx4){0.f, 0.f, 0.f, 0.f};
#pragma unroll
  for (int kk = 0; kk < 4; ++kk) {
    bf16x8 nO[8];
    if (kk < 3) {
#pragma unroll
      for (int nt = 0; nt < 8; ++nt) nO[nt] = WFRAG(3, nt, kk + 1);
    }
#pragma unroll
    for (int nt = 0; nt < 8; ++nt)
      oacc[nt] = __builtin_amdgcn_mfma_f32_16x16x32_bf16(hfr[kk], fO[nt], oacc[nt], 0, 0, 0);
    if (kk < 3) {
#pragma unroll
      for (int nt = 0; nt < 8; ++nt) fO[nt] = nO[nt];
    }
  }

#pragma unroll
  for (int nt = 0; nt < 8; ++nt)
#pragma unroll
    for (int i = 0; i < 4; ++i) {
      int row = 16 * w + 4 * g + i;
      out[((long)bc * CK + row) * D_ + 16 * nt + c] = oacc[nt][i] + yx[row];
    }
}

extern "C" void kernel_launch(void* const* d_in, const int* in_sizes, int n_in,
                              void* d_out, int out_size, void* d_ws, size_t ws_size,
                              hipStream_t stream) {
  const float* x    = (const float*)d_in[0];
  const float* logA = (const float*)d_in[1];
  const float* W_B  = (const float*)d_in[2];
  const float* W_C  = (const float*)d_in[3];
  const float* W_dt = (const float*)d_in[4];
  const float* b_dt = (const float*)d_in[5];
  const float* W_out= (const float*)d_in[6];
  float* out = (float*)d_out;
  float* ws  = (float*)d_ws;

  k0_prep<<<16, 256, 0, stream>>>(W_dt, W_B, W_C, W_out, logA, ws);
  k1_carry<<<NCHUNK, 256, 0, stream>>>(x, b_dt, ws);
  k3_carry<<<B_, 128, 0, stream>>>(ws);
  k4_main<<<NCHUNK, 256, 0, stream>>>(x, b_dt, out, ws);
}

// Round 4
// 152.454 us; speedup vs baseline: 1.9060x; 1.3040x over previous
//
#include <hip/hip_runtime.h>
#include <hip/hip_bf16.h>

// Problem constants
#define B_ 8
#define T_ 8192
#define D_ 128
#define S_ 128
#define CK 64
#define NC 128           // T_/CK
#define NCHUNK (B_*NC)   // 1024

typedef __attribute__((ext_vector_type(8))) __bf16 bf16x8;
typedef __attribute__((ext_vector_type(4))) float floatx4;

// ws layout (floats). Weights (fragment-swizzled bf16) + carries (~1.7 MB).
#define WS_WBF     0                        // 4 mats bf16 = 65536 ushort = 32768 floats
#define WS_AVEC    32768                    // 128
#define WS_CARRYA  32896                    // NCHUNK*128
#define WS_CARRYH  (WS_CARRYA + 131072)
#define WS_H0      (WS_CARRYH + 131072)

__device__ __forceinline__ unsigned short f2bf(float f) {
  __hip_bfloat16 b = __float2bfloat16(f);
  return *(unsigned short*)&b;
}

__device__ __forceinline__ float softplus1(float z) {
  float sp = fmaxf(z, 0.0f) + __logf(1.0f + __expf(-fabsf(z)));
  return fminf(sp, 1.0f);
}

// ---------------- K0: weights -> bf16 in MFMA B-fragment order ----------------
// layout: wb[(((m*8+nt)*4+kk)*64 + lane)*8 + e]  <-  W_m[16nt + (lane&15)][32kk + 8*(lane>>4) + e]
// so each (m,nt,kk) fragment is a contiguous 1KB block read by one wave-load.
__global__ __launch_bounds__(256) void k0_prep(
    const float* __restrict__ Wdt, const float* __restrict__ WB,
    const float* __restrict__ WC,  const float* __restrict__ Wout,
    const float* __restrict__ logA, float* __restrict__ ws) {
  unsigned short* wb = (unsigned short*)(ws + WS_WBF);
  const float* srcs[4] = {Wdt, WB, WC, Wout};
  int gid = blockIdx.x * 256 + threadIdx.x;   // 0..4095
#pragma unroll
  for (int r = 0; r < 2; ++r) {
    int fid = gid * 2 + r;                    // 0..8191 fragment-lane groups
    int lane = fid & 63;
    int kk   = (fid >> 6) & 3;
    int nt   = (fid >> 8) & 7;
    int m    = fid >> 11;
    int c = lane & 15, g = lane >> 4;
    const float* src = srcs[m] + (16 * nt + c) * 128 + 32 * kk + 8 * g;
    float4 v0 = *(const float4*)src;
    float4 v1 = *(const float4*)(src + 4);
    unsigned short o[8];
    o[0] = f2bf(v0.x); o[1] = f2bf(v0.y); o[2] = f2bf(v0.z); o[3] = f2bf(v0.w);
    o[4] = f2bf(v1.x); o[5] = f2bf(v1.y); o[6] = f2bf(v1.z); o[7] = f2bf(v1.w);
    *(ushort4*)&wb[fid * 8]     = *(ushort4*)&o[0];
    *(ushort4*)&wb[fid * 8 + 4] = *(ushort4*)&o[4];
  }
  if (blockIdx.x == 0 && threadIdx.x < 128)
    ws[WS_AVEC + threadIdx.x] = -fminf(expf(logA[threadIdx.x]), 10.0f);
}

// fragment load: contiguous 1KB per wave
#define WFRAG(mat, nt, kk) \
  (*(const bf16x8*)&wb[(((((mat) * 8 + (nt)) * 4) + (kk)) * 64 + lane) * 8])

// ---------------- K1: carry-only kernel ----------------
__global__ __launch_bounds__(256, 2) void k1_carry(
    const float* __restrict__ x, const float* __restrict__ bdt,
    float* __restrict__ ws) {
  __shared__ __align__(16) unsigned short xb[64 * 136];  // bf16 [t][d] pad 8
  __shared__ float wlsP[4 * 128];
  __shared__ float wlsH[4 * 128];

  const int tid  = threadIdx.x;
  const int bc   = blockIdx.x;
  const int w    = tid >> 6;
  const int lane = tid & 63;
  const int g    = lane >> 4;
  const int c    = lane & 15;

  float Av[8], Bd[8];
#pragma unroll
  for (int nt = 0; nt < 8; ++nt) {
    Av[nt] = ws[WS_AVEC + 16 * nt + c];
    Bd[nt] = bdt[16 * nt + c];
  }

  const float4* x4 = (const float4*)(x + (long)bc * CK * D_);
#pragma unroll
  for (int i = 0; i < 8; ++i) {
    int f4 = tid + 256 * i;
    int t  = f4 >> 5;
    int d0 = (f4 & 31) << 2;
    float4 v = x4[f4];
    ushort4 o;
    o.x = f2bf(v.x); o.y = f2bf(v.y); o.z = f2bf(v.z); o.w = f2bf(v.w);
    *(ushort4*)&xb[t * 136 + d0] = o;
  }
  __syncthreads();

  bf16x8 afr[4];
#pragma unroll
  for (int kk = 0; kk < 4; ++kk)
    afr[kk] = *(const bf16x8*)&xb[(16 * w + c) * 136 + 8 * g + 32 * kk];

  const unsigned short* wb = (const unsigned short*)(ws + WS_WBF);

  floatx4 dtacc[8], bacc[8];
#pragma unroll
  for (int nt = 0; nt < 8; ++nt) {
    dtacc[nt] = (floatx4){0.f, 0.f, 0.f, 0.f};
    bacc[nt]  = (floatx4){0.f, 0.f, 0.f, 0.f};
  }

  bf16x8 fD[8], fB[8];
#pragma unroll
  for (int nt = 0; nt < 8; ++nt) fD[nt] = WFRAG(0, nt, 0);
#pragma unroll
  for (int nt = 0; nt < 8; ++nt) fB[nt] = WFRAG(1, nt, 0);
#pragma unroll
  for (int kk = 0; kk < 4; ++kk) {
    bf16x8 nD[8], nB[8];
    if (kk < 3) {
#pragma unroll
      for (int nt = 0; nt < 8; ++nt) nD[nt] = WFRAG(0, nt, kk + 1);
#pragma unroll
      for (int nt = 0; nt < 8; ++nt) nB[nt] = WFRAG(1, nt, kk + 1);
    }
#pragma unroll
    for (int nt = 0; nt < 8; ++nt) {
      dtacc[nt] = __builtin_amdgcn_mfma_f32_16x16x32_bf16(afr[kk], fD[nt], dtacc[nt], 0, 0, 0);
      bacc[nt]  = __builtin_amdgcn_mfma_f32_16x16x32_bf16(afr[kk], fB[nt], bacc[nt], 0, 0, 0);
    }
    if (kk < 3) {
#pragma unroll
      for (int nt = 0; nt < 8; ++nt) { fD[nt] = nD[nt]; fB[nt] = nB[nt]; }
    }
  }

  float P[8], H[8];
#pragma unroll
  for (int nt = 0; nt < 8; ++nt) {
    float Pl = 1.0f, Hl = 0.0f;
#pragma unroll
    for (int i = 0; i < 4; ++i) {
      float dt = softplus1(dtacc[nt][i] + Bd[nt]);
      float u  = bacc[nt][i] * dt;
      float la = fmaxf(fminf(dt * Av[nt], 0.0f), -0.5f);
      float a  = __expf(la);
      Hl = fmaf(a, Hl, u);
      Pl = Pl * a;
    }
    P[nt] = Pl; H[nt] = Hl;
  }

#pragma unroll
  for (int nt = 0; nt < 8; ++nt) {
    float Po = __shfl(P[nt], (lane - 16) & 63), Ho = __shfl(H[nt], (lane - 16) & 63);
    if (g >= 1) { H[nt] = fmaf(Ho, P[nt], H[nt]); P[nt] = Po * P[nt]; }
    Po = __shfl(P[nt], (lane - 32) & 63); Ho = __shfl(H[nt], (lane - 32) & 63);
    if (g >= 2) { H[nt] = fmaf(Ho, P[nt], H[nt]); P[nt] = Po * P[nt]; }
    if (g == 3) {
      wlsP[w * 128 + 16 * nt + c] = P[nt];
      wlsH[w * 128 + 16 * nt + c] = H[nt];
    }
  }
  __syncthreads();

  if (w == 3 && g == 3) {
#pragma unroll
    for (int nt = 0; nt < 8; ++nt) {
      float Pe = 1.0f, He = 0.0f;
#pragma unroll
      for (int ww = 0; ww < 3; ++ww) {
        float Pw = wlsP[ww * 128 + 16 * nt + c];
        float Hw = wlsH[ww * 128 + 16 * nt + c];
        He = fmaf(He, Pw, Hw);
        Pe = Pe * Pw;
      }
      ws[WS_CARRYA + bc * 128 + 16 * nt + c] = P[nt] * Pe;
      ws[WS_CARRYH + bc * 128 + 16 * nt + c] = fmaf(P[nt], He, H[nt]);
    }
  }
}

// ---------------- K3: carry scan over chunks ----------------
__global__ __launch_bounds__(128) void k3_carry(float* __restrict__ ws) {
  const int b = blockIdx.x;
  const int s = threadIdx.x;
  const float* cA = ws + WS_CARRYA + b * NC * S_ + s;
  const float* cH = ws + WS_CARRYH + b * NC * S_ + s;
  float* H0 = ws + WS_H0 + b * NC * S_ + s;
  float H = 0.0f;
  float pa[16], ph[16];
#pragma unroll
  for (int j = 0; j < 16; ++j) { pa[j] = cA[j * S_]; ph[j] = cH[j * S_]; }
  for (int cb = 0; cb < 8; ++cb) {
    float na[16], nh[16];
    if (cb < 7) {
#pragma unroll
      for (int j = 0; j < 16; ++j) {
        na[j] = cA[(cb * 16 + 16 + j) * S_];
        nh[j] = cH[(cb * 16 + 16 + j) * S_];
      }
    }
#pragma unroll
    for (int j = 0; j < 16; ++j) {
      H0[(cb * 16 + j) * S_] = H;
      H = fmaf(pa[j], H, ph[j]);
    }
#pragma unroll
    for (int j = 0; j < 16; ++j) { pa[j] = na[j]; ph[j] = nh[j]; }
  }
}

// ---------------- K4: recompute + scan + fixup + y + out GEMM ----------------
__global__ __launch_bounds__(256, 2) void k4_main(
    const float* __restrict__ x, const float* __restrict__ bdt,
    float* __restrict__ out, float* __restrict__ ws) {
  __shared__ __align__(16) unsigned short xb[64 * 136];  // x bf16, reused as hT
  __shared__ float wlsP[4 * 128];
  __shared__ float wlsH[4 * 128];
  __shared__ float yx[64];

  const int tid  = threadIdx.x;
  const int bc   = blockIdx.x;
  const int w    = tid >> 6;
  const int lane = tid & 63;
  const int g    = lane >> 4;
  const int c    = lane & 15;

  float Av[8], Bd[8], h0[8];
#pragma unroll
  for (int nt = 0; nt < 8; ++nt) {
    Av[nt] = ws[WS_AVEC + 16 * nt + c];
    Bd[nt] = bdt[16 * nt + c];
    h0[nt] = ws[WS_H0 + bc * 128 + 16 * nt + c];
  }
  float x0[4];
  if (c == 0) {
#pragma unroll
    for (int i = 0; i < 4; ++i)
      x0[i] = x[((long)bc * CK + 16 * w + 4 * g + i) * D_];
  }

  const float4* x4 = (const float4*)(x + (long)bc * CK * D_);
#pragma unroll
  for (int i = 0; i < 8; ++i) {
    int f4 = tid + 256 * i;
    int t  = f4 >> 5;
    int d0 = (f4 & 31) << 2;
    float4 v = x4[f4];
    ushort4 o;
    o.x = f2bf(v.x); o.y = f2bf(v.y); o.z = f2bf(v.z); o.w = f2bf(v.w);
    *(ushort4*)&xb[t * 136 + d0] = o;
  }
  __syncthreads();

  bf16x8 afr[4];
#pragma unroll
  for (int kk = 0; kk < 4; ++kk)
    afr[kk] = *(const bf16x8*)&xb[(16 * w + c) * 136 + 8 * g + 32 * kk];

  const unsigned short* wb = (const unsigned short*)(ws + WS_WBF);

  floatx4 dtacc[8], bacc[8];
#pragma unroll
  for (int nt = 0; nt < 8; ++nt) {
    dtacc[nt] = (floatx4){0.f, 0.f, 0.f, 0.f};
    bacc[nt]  = (floatx4){0.f, 0.f, 0.f, 0.f};
  }

  {
    bf16x8 fD[8], fB[8];
#pragma unroll
    for (int nt = 0; nt < 8; ++nt) fD[nt] = WFRAG(0, nt, 0);
#pragma unroll
    for (int nt = 0; nt < 8; ++nt) fB[nt] = WFRAG(1, nt, 0);
#pragma unroll
    for (int kk = 0; kk < 4; ++kk) {
      bf16x8 nD[8], nB[8];
      if (kk < 3) {
#pragma unroll
        for (int nt = 0; nt < 8; ++nt) nD[nt] = WFRAG(0, nt, kk + 1);
#pragma unroll
        for (int nt = 0; nt < 8; ++nt) nB[nt] = WFRAG(1, nt, kk + 1);
      }
#pragma unroll
      for (int nt = 0; nt < 8; ++nt) {
        dtacc[nt] = __builtin_amdgcn_mfma_f32_16x16x32_bf16(afr[kk], fD[nt], dtacc[nt], 0, 0, 0);
        bacc[nt]  = __builtin_amdgcn_mfma_f32_16x16x32_bf16(afr[kk], fB[nt], bacc[nt], 0, 0, 0);
      }
      if (kk < 3) {
#pragma unroll
        for (int nt = 0; nt < 8; ++nt) { fD[nt] = nD[nt]; fB[nt] = nB[nt]; }
      }
    }
  }

  bf16x8 fC[8];
#pragma unroll
  for (int nt = 0; nt < 8; ++nt) fC[nt] = WFRAG(2, nt, 0);

#pragma unroll
  for (int nt = 0; nt < 8; ++nt)
#pragma unroll
    for (int i = 0; i < 4; ++i) {
      float dt = softplus1(dtacc[nt][i] + Bd[nt]);
      float u  = bacc[nt][i] * dt;
      float la = fmaxf(fminf(dt * Av[nt], 0.0f), -0.5f);
      dtacc[nt][i] = __expf(la);   // a
      bacc[nt][i]  = u;            // u
    }

  floatx4 cacc[8];
#pragma unroll
  for (int nt = 0; nt < 8; ++nt) cacc[nt] = (floatx4){0.f, 0.f, 0.f, 0.f};
#pragma unroll
  for (int kk = 0; kk < 4; ++kk) {
    bf16x8 nC[8];
    if (kk < 3) {
#pragma unroll
      for (int nt = 0; nt < 8; ++nt) nC[nt] = WFRAG(2, nt, kk + 1);
    }
#pragma unroll
    for (int nt = 0; nt < 8; ++nt)
      cacc[nt] = __builtin_amdgcn_mfma_f32_16x16x32_bf16(afr[kk], fC[nt], cacc[nt], 0, 0, 0);
    if (kk < 3) {
#pragma unroll
      for (int nt = 0; nt < 8; ++nt) fC[nt] = nC[nt];
    }
  }

  // hierarchical scan
#pragma unroll
  for (int nt = 0; nt < 8; ++nt) {
    float P = dtacc[nt][0], H = bacc[nt][0];
#pragma unroll
    for (int i = 1; i < 4; ++i) {
      H = fmaf(H, dtacc[nt][i], bacc[nt][i]);
      P = P * dtacc[nt][i];
      dtacc[nt][i] = P;
      bacc[nt][i]  = H;
    }
  }
#pragma unroll
  for (int nt = 0; nt < 8; ++nt) {
    float P = dtacc[nt][3], H = bacc[nt][3];
    float Po = __shfl(P, (lane - 16) & 63), Ho = __shfl(H, (lane - 16) & 63);
    if (g >= 1) { H = fmaf(Ho, P, H); P = Po * P; }
    Po = __shfl(P, (lane - 32) & 63); Ho = __shfl(H, (lane - 32) & 63);
    if (g >= 2) { H = fmaf(Ho, P, H); P = Po * P; }
    float Pe = __shfl(P, (lane - 16) & 63), He = __shfl(H, (lane - 16) & 63);
    if (g == 0) { Pe = 1.0f; He = 0.0f; }
#pragma unroll
    for (int i = 0; i < 4; ++i) {
      bacc[nt][i] = fmaf(dtacc[nt][i], He, bacc[nt][i]);
      dtacc[nt][i] = dtacc[nt][i] * Pe;
    }
    if (g == 3) {
      wlsP[w * 128 + 16 * nt + c] = dtacc[nt][3];
      wlsH[w * 128 + 16 * nt + c] = bacc[nt][3];
    }
  }
  __syncthreads();
#pragma unroll
  for (int nt = 0; nt < 8; ++nt) {
    float Pe = 1.0f, He = 0.0f;
    for (int ww = 0; ww < 3; ++ww) {
      if (ww < w) {
        float Pw = wlsP[ww * 128 + 16 * nt + c];
        float Hw = wlsH[ww * 128 + 16 * nt + c];
        He = fmaf(He, Pw, Hw);
        Pe = Pe * Pw;
      }
    }
#pragma unroll
    for (int i = 0; i < 4; ++i) {
      bacc[nt][i] = fmaf(dtacc[nt][i], He, bacc[nt][i]);   // h_local
      dtacc[nt][i] = dtacc[nt][i] * Pe;                    // cumP
    }
  }

  // fixup + y + hT
  float yv[4] = {0.f, 0.f, 0.f, 0.f};
  unsigned short* hT = xb;
#pragma unroll
  for (int nt = 0; nt < 8; ++nt)
#pragma unroll
    for (int i = 0; i < 4; ++i) {
      float hv = fmaf(dtacc[nt][i], h0[nt], bacc[nt][i]);
      yv[i] = fmaf(cacc[nt][i], hv, yv[i]);
      hT[(16 * w + 4 * g + i) * 136 + 16 * nt + c] = f2bf(hv);
    }
#pragma unroll
  for (int i = 0; i < 4; ++i) {
    yv[i] += __shfl_xor(yv[i], 1);
    yv[i] += __shfl_xor(yv[i], 2);
    yv[i] += __shfl_xor(yv[i], 4);
    yv[i] += __shfl_xor(yv[i], 8);
  }
  if (c == 0) {
#pragma unroll
    for (int i = 0; i < 4; ++i) yx[16 * w + 4 * g + i] = yv[i] * x0[i];
  }

  bf16x8 fO[8];
#pragma unroll
  for (int nt = 0; nt < 8; ++nt) fO[nt] = WFRAG(3, nt, 0);
  __syncthreads();

  bf16x8 hfr[4];
#pragma unroll
  for (int kk = 0; kk < 4; ++kk)
    hfr[kk] = *(const bf16x8*)&hT[(16 * w + c) * 136 + 8 * g + 32 * kk];

  floatx4 oacc[8];
#pragma unroll
  for (int nt = 0; nt < 8; ++nt) oacc[nt] = (floatx4){0.f, 0.f, 0.f, 0.f};
#pragma unroll
  for (int kk = 0; kk < 4; ++kk) {
    bf16x8 nO[8];
    if (kk < 3) {
#pragma unroll
      for (int nt = 0; nt < 8; ++nt) nO[nt] = WFRAG(3, nt, kk + 1);
    }
#pragma unroll
    for (int nt = 0; nt < 8; ++nt)
      oacc[nt] = __builtin_amdgcn_mfma_f32_16x16x32_bf16(hfr[kk], fO[nt], oacc[nt], 0, 0, 0);
    if (kk < 3) {
#pragma unroll
      for (int nt = 0; nt < 8; ++nt) fO[nt] = nO[nt];
    }
  }

#pragma unroll
  for (int nt = 0; nt < 8; ++nt)
#pragma unroll
    for (int i = 0; i < 4; ++i) {
      int row = 16 * w + 4 * g + i;
      out[((long)bc * CK + row) * D_ + 16 * nt + c] = oacc[nt][i] + yx[row];
    }
}

extern "C" void kernel_launch(void* const* d_in, const int* in_sizes, int n_in,
                              void* d_out, int out_size, void* d_ws, size_t ws_size,
                              hipStream_t stream) {
  const float* x    = (const float*)d_in[0];
  const float* logA = (const float*)d_in[1];
  const float* W_B  = (const float*)d_in[2];
  const float* W_C  = (const float*)d_in[3];
  const float* W_dt = (const float*)d_in[4];
  const float* b_dt = (const float*)d_in[5];
  const float* W_out= (const float*)d_in[6];
  float* out = (float*)d_out;
  float* ws  = (float*)d_ws;

  k0_prep<<<16, 256, 0, stream>>>(W_dt, W_B, W_C, W_out, logA, ws);
  k1_carry<<<NCHUNK, 256, 0, stream>>>(x, b_dt, ws);
  k3_carry<<<B_, 128, 0, stream>>>(ws);
  k4_main<<<NCHUNK, 256, 0, stream>>>(x, b_dt, out, ws);
}

// Round 6
// 133.387 us; speedup vs baseline: 2.1785x; 1.1429x over previous
//
#include <hip/hip_runtime.h>
#include <hip/hip_bf16.h>

// Problem constants
#define B_ 8
#define T_ 8192
#define D_ 128
#define S_ 128
#define CK 64
#define NC 128           // T_/CK
#define NCHUNK (B_*NC)   // 1024

typedef __attribute__((ext_vector_type(8))) __bf16 bf16x8;
typedef __attribute__((ext_vector_type(4))) float floatx4;

// ws layout (floats)
#define WS_WBF     0                        // 4 mats bf16 (frag-swizzled) = 32768 floats
#define WS_AVEC    32768                    // 128
#define WS_PART    32896                    // u64[NCHUNK*128] partial carries = 262144 floats

__device__ __forceinline__ unsigned short f2bf(float f) {
  __hip_bfloat16 b = __float2bfloat16(f);
  return *(unsigned short*)&b;
}

__device__ __forceinline__ float softplus1(float z) {
  float sp = fmaxf(z, 0.0f) + __logf(1.0f + __expf(-fabsf(z)));
  return fminf(sp, 1.0f);
}

__device__ __forceinline__ unsigned long long part_load(const unsigned long long* p) {
  return __hip_atomic_load(p, __ATOMIC_RELAXED, __HIP_MEMORY_SCOPE_AGENT);
}
__device__ __forceinline__ void part_store(unsigned long long* p, unsigned long long v) {
  __hip_atomic_store(p, v, __ATOMIC_RELAXED, __HIP_MEMORY_SCOPE_AGENT);
}

// ---------------- K0: weights -> bf16 fragment order; zero partials ----------------
// wb[(((m*8+nt)*4+kk)*64 + lane)*8 + e] <- W_m[16nt + (lane&15)][32kk + 8*(lane>>4) + e]
__global__ __launch_bounds__(256) void k0_prep(
    const float* __restrict__ Wdt, const float* __restrict__ WB,
    const float* __restrict__ WC,  const float* __restrict__ Wout,
    const float* __restrict__ logA, float* __restrict__ ws) {
  unsigned short* wb = (unsigned short*)(ws + WS_WBF);
  const float* srcs[4] = {Wdt, WB, WC, Wout};
  int gid = blockIdx.x * 256 + threadIdx.x;   // 0..4095
#pragma unroll
  for (int r = 0; r < 2; ++r) {
    int fid = gid * 2 + r;                    // 0..8191
    int lane = fid & 63;
    int kk   = (fid >> 6) & 3;
    int nt   = (fid >> 8) & 7;
    int m    = fid >> 11;
    int c = lane & 15, g = lane >> 4;
    const float* src = srcs[m] + (16 * nt + c) * 128 + 32 * kk + 8 * g;
    float4 v0 = *(const float4*)src;
    float4 v1 = *(const float4*)(src + 4);
    unsigned short o[8];
    o[0] = f2bf(v0.x); o[1] = f2bf(v0.y); o[2] = f2bf(v0.z); o[3] = f2bf(v0.w);
    o[4] = f2bf(v1.x); o[5] = f2bf(v1.y); o[6] = f2bf(v1.z); o[7] = f2bf(v1.w);
    *(ushort4*)&wb[fid * 8]     = *(ushort4*)&o[0];
    *(ushort4*)&wb[fid * 8 + 4] = *(ushort4*)&o[4];
  }
  // zero the partials array (ws is poisoned 0xAA before every call)
  unsigned long long* part = (unsigned long long*)(ws + WS_PART);
#pragma unroll
  for (int i = 0; i < 32; ++i)
    part[gid + 4096 * i] = 0ull;
  if (blockIdx.x == 0 && threadIdx.x < 128)
    ws[WS_AVEC + threadIdx.x] = -fminf(expf(logA[threadIdx.x]), 10.0f);
}

// fragment load: contiguous 1KB per wave
#define WFRAG(mat, nt, kk) \
  (*(const bf16x8*)&wb[(((((mat) * 8 + (nt)) * 4) + (kk)) * 64 + lane) * 8])

// ---------------- K_MAIN: fused kernel with decoupled-lookback scan ----------------
// bc = blockIdx.x ; b = bc&7 (chain), cidx = bc>>3 (position in chain).
// Predecessors of (b,cidx) have strictly smaller blockIdx -> lookback is
// deadlock-free under ascending dispatch (rocPRIM assumption), independent
// of how many blocks are co-resident.
__global__ __launch_bounds__(256, 2) void k_main(
    const float* __restrict__ x, const float* __restrict__ bdt,
    float* __restrict__ out, float* __restrict__ ws) {
  __shared__ __align__(16) unsigned short xb[64 * 136];  // x bf16, reused as hT
  __shared__ float wlsP[4 * 128];
  __shared__ float wlsH[4 * 128];
  __shared__ float h0buf[128];
  __shared__ float yx[64];

  const int tid  = threadIdx.x;
  const int bc   = blockIdx.x;
  const int b    = bc & 7;
  const int cidx = bc >> 3;
  const long chunk_t0 = (long)b * T_ + (long)cidx * CK;   // global t of row 0
  const int w    = tid >> 6;
  const int lane = tid & 63;
  const int g    = lane >> 4;
  const int c    = lane & 15;

  float Av[8], Bd[8];
#pragma unroll
  for (int nt = 0; nt < 8; ++nt) {
    Av[nt] = ws[WS_AVEC + 16 * nt + c];
    Bd[nt] = bdt[16 * nt + c];
  }
  float x0[4];
  if (c == 0) {
#pragma unroll
    for (int i = 0; i < 4; ++i)
      x0[i] = x[(chunk_t0 + 16 * w + 4 * g + i) * D_];
  }

  // ---- stage x -> bf16 LDS ----
  const float4* x4 = (const float4*)(x + chunk_t0 * D_);
#pragma unroll
  for (int i = 0; i < 8; ++i) {
    int f4 = tid + 256 * i;
    int t  = f4 >> 5;
    int d0 = (f4 & 31) << 2;
    float4 v = x4[f4];
    ushort4 o;
    o.x = f2bf(v.x); o.y = f2bf(v.y); o.z = f2bf(v.z); o.w = f2bf(v.w);
    *(ushort4*)&xb[t * 136 + d0] = o;
  }
  __syncthreads();

  bf16x8 afr[4];
#pragma unroll
  for (int kk = 0; kk < 4; ++kk)
    afr[kk] = *(const bf16x8*)&xb[(16 * w + c) * 136 + 8 * g + 32 * kk];

  const unsigned short* wb = (const unsigned short*)(ws + WS_WBF);
  unsigned long long* part = (unsigned long long*)(ws + WS_PART);

  floatx4 dtacc[8], bacc[8];
#pragma unroll
  for (int nt = 0; nt < 8; ++nt) {
    dtacc[nt] = (floatx4){0.f, 0.f, 0.f, 0.f};
    bacc[nt]  = (floatx4){0.f, 0.f, 0.f, 0.f};
  }

  {  // dt + B GEMMs with lookahead
    bf16x8 fD[8], fB[8];
#pragma unroll
    for (int nt = 0; nt < 8; ++nt) fD[nt] = WFRAG(0, nt, 0);
#pragma unroll
    for (int nt = 0; nt < 8; ++nt) fB[nt] = WFRAG(1, nt, 0);
#pragma unroll
    for (int kk = 0; kk < 4; ++kk) {
      bf16x8 nD[8], nB[8];
      if (kk < 3) {
#pragma unroll
        for (int nt = 0; nt < 8; ++nt) nD[nt] = WFRAG(0, nt, kk + 1);
#pragma unroll
        for (int nt = 0; nt < 8; ++nt) nB[nt] = WFRAG(1, nt, kk + 1);
      }
#pragma unroll
      for (int nt = 0; nt < 8; ++nt) {
        dtacc[nt] = __builtin_amdgcn_mfma_f32_16x16x32_bf16(afr[kk], fD[nt], dtacc[nt], 0, 0, 0);
        bacc[nt]  = __builtin_amdgcn_mfma_f32_16x16x32_bf16(afr[kk], fB[nt], bacc[nt], 0, 0, 0);
      }
      if (kk < 3) {
#pragma unroll
        for (int nt = 0; nt < 8; ++nt) { fD[nt] = nD[nt]; fB[nt] = nB[nt]; }
      }
    }
  }

  // elementwise -> a (dtacc), u (bacc)
#pragma unroll
  for (int nt = 0; nt < 8; ++nt)
#pragma unroll
    for (int i = 0; i < 4; ++i) {
      float dt = softplus1(dtacc[nt][i] + Bd[nt]);
      float u  = bacc[nt][i] * dt;
      float la = fmaxf(fminf(dt * Av[nt], 0.0f), -0.5f);
      dtacc[nt][i] = __expf(la);   // a
      bacc[nt][i]  = u;            // u
    }

  // ---- local scan: intra-lane prefixes ----
#pragma unroll
  for (int nt = 0; nt < 8; ++nt) {
    float P = dtacc[nt][0], H = bacc[nt][0];
#pragma unroll
    for (int i = 1; i < 4; ++i) {
      H = fmaf(H, dtacc[nt][i], bacc[nt][i]);
      P = P * dtacc[nt][i];
      dtacc[nt][i] = P;
      bacc[nt][i]  = H;
    }
  }
  // Kogge-Stone over g-segments; wave totals into wls
#pragma unroll
  for (int nt = 0; nt < 8; ++nt) {
    float P = dtacc[nt][3], H = bacc[nt][3];
    float Po = __shfl(P, (lane - 16) & 63), Ho = __shfl(H, (lane - 16) & 63);
    if (g >= 1) { H = fmaf(Ho, P, H); P = Po * P; }
    Po = __shfl(P, (lane - 32) & 63); Ho = __shfl(H, (lane - 32) & 63);
    if (g >= 2) { H = fmaf(Ho, P, H); P = Po * P; }
    float Pe = __shfl(P, (lane - 16) & 63), He = __shfl(H, (lane - 16) & 63);
    if (g == 0) { Pe = 1.0f; He = 0.0f; }
#pragma unroll
    for (int i = 0; i < 4; ++i) {
      bacc[nt][i] = fmaf(dtacc[nt][i], He, bacc[nt][i]);   // wave-local incl H
      dtacc[nt][i] = dtacc[nt][i] * Pe;                    // wave-local incl P
    }
    if (g == 3) {
      wlsP[w * 128 + 16 * nt + c] = dtacc[nt][3];
      wlsH[w * 128 + 16 * nt + c] = bacc[nt][3];
    }
  }
  __syncthreads();

  // ---- publish this chunk's carry ASAP (threads 0..127, s = tid) ----
  if (tid < 128) {
    float Pt = 1.0f, Ht = 0.0f;
#pragma unroll
    for (int ww = 0; ww < 4; ++ww) {
      float Pw = wlsP[ww * 128 + tid];
      float Hw = wlsH[ww * 128 + tid];
      Ht = fmaf(Ht, Pw, Hw);
      Pt = Pt * Pw;
    }
    unsigned long long v = ((unsigned long long)__float_as_uint(Ht) << 32) |
                           (unsigned long long)__float_as_uint(Pt);
    part_store(&part[bc * 128 + tid], v);
  }

  // ---- inter-wave exclusive fix (registers -> chunk-local cumP / h_local) ----
#pragma unroll
  for (int nt = 0; nt < 8; ++nt) {
    float Pe = 1.0f, He = 0.0f;
    for (int ww = 0; ww < 3; ++ww) {
      if (ww < w) {
        float Pw = wlsP[ww * 128 + 16 * nt + c];
        float Hw = wlsH[ww * 128 + 16 * nt + c];
        He = fmaf(He, Pw, Hw);
        Pe = Pe * Pw;
      }
    }
#pragma unroll
    for (int i = 0; i < 4; ++i) {
      bacc[nt][i] = fmaf(dtacc[nt][i], He, bacc[nt][i]);   // h_local (chunk-incl)
      dtacc[nt][i] = dtacc[nt][i] * Pe;                    // cumP (chunk-incl)
    }
  }

  // ---- C GEMM (independent; overlaps neighbors' publishes) ----
  floatx4 cacc[8];
#pragma unroll
  for (int nt = 0; nt < 8; ++nt) cacc[nt] = (floatx4){0.f, 0.f, 0.f, 0.f};
  {
    bf16x8 fC[8];
#pragma unroll
    for (int nt = 0; nt < 8; ++nt) fC[nt] = WFRAG(2, nt, 0);
#pragma unroll
    for (int kk = 0; kk < 4; ++kk) {
      bf16x8 nC[8];
      if (kk < 3) {
#pragma unroll
        for (int nt = 0; nt < 8; ++nt) nC[nt] = WFRAG(2, nt, kk + 1);
      }
#pragma unroll
      for (int nt = 0; nt < 8; ++nt)
        cacc[nt] = __builtin_amdgcn_mfma_f32_16x16x32_bf16(afr[kk], fC[nt], cacc[nt], 0, 0, 0);
      if (kk < 3) {
#pragma unroll
        for (int nt = 0; nt < 8; ++nt) fC[nt] = nC[nt];
      }
    }
  }

  __syncthreads();   // wls reads done before h0buf/hT writes below

  // ---- decoupled lookback (threads 0..127, s = tid) ----
  if (tid < 128) {
    float RP = 1.0f, RH = 0.0f;
    int j = cidx - 1;
    while (j >= 0) {
      int nb = (j >= 7) ? 8 : (j + 1);
      unsigned long long v[8];
#pragma unroll
      for (int q = 0; q < 8; ++q)
        if (q < nb) v[q] = part_load(&part[(((j - q) << 3) | b) * 128 + tid]);
#pragma unroll
      for (int q = 0; q < 8; ++q) {
        if (q < nb) {
          unsigned long long vv = v[q];
          const unsigned long long* ap = &part[(((j - q) << 3) | b) * 128 + tid];
          while ((unsigned)vv == 0u) {         // P>0 always => low word != 0 when ready
            __builtin_amdgcn_s_sleep(2);
            vv = part_load(ap);
          }
          float Pj = __uint_as_float((unsigned)vv);
          float Hj = __uint_as_float((unsigned)(vv >> 32));
          RH = fmaf(RP, Hj, RH);
          RP = RP * Pj;
        }
      }
      j -= nb;
    }
    h0buf[tid] = RH;    // state entering this chunk
  }
  __syncthreads();

  // ---- fixup h = h_local + cumP*H0, y, hT ----
  float h0[8];
#pragma unroll
  for (int nt = 0; nt < 8; ++nt) h0[nt] = h0buf[16 * nt + c];

  float yv[4] = {0.f, 0.f, 0.f, 0.f};
  unsigned short* hT = xb;
#pragma unroll
  for (int nt = 0; nt < 8; ++nt)
#pragma unroll
    for (int i = 0; i < 4; ++i) {
      float hv = fmaf(dtacc[nt][i], h0[nt], bacc[nt][i]);
      yv[i] = fmaf(cacc[nt][i], hv, yv[i]);
      hT[(16 * w + 4 * g + i) * 136 + 16 * nt + c] = f2bf(hv);
    }
#pragma unroll
  for (int i = 0; i < 4; ++i) {
    yv[i] += __shfl_xor(yv[i], 1);
    yv[i] += __shfl_xor(yv[i], 2);
    yv[i] += __shfl_xor(yv[i], 4);
    yv[i] += __shfl_xor(yv[i], 8);
  }
  if (c == 0) {
#pragma unroll
    for (int i = 0; i < 4; ++i) yx[16 * w + 4 * g + i] = yv[i] * x0[i];
  }

  bf16x8 fO[8];
#pragma unroll
  for (int nt = 0; nt < 8; ++nt) fO[nt] = WFRAG(3, nt, 0);
  __syncthreads();

  // ---- out GEMM: A = h bf16 [t][s], B = Wout [d][s] ----
  bf16x8 hfr[4];
#pragma unroll
  for (int kk = 0; kk < 4; ++kk)
    hfr[kk] = *(const bf16x8*)&hT[(16 * w + c) * 136 + 8 * g + 32 * kk];

  floatx4 oacc[8];
#pragma unroll
  for (int nt = 0; nt < 8; ++nt) oacc[nt] = (floatx4){0.f, 0.f, 0.f, 0.f};
#pragma unroll
  for (int kk = 0; kk < 4; ++kk) {
    bf16x8 nO[8];
    if (kk < 3) {
#pragma unroll
      for (int nt = 0; nt < 8; ++nt) nO[nt] = WFRAG(3, nt, kk + 1);
    }
#pragma unroll
    for (int nt = 0; nt < 8; ++nt)
      oacc[nt] = __builtin_amdgcn_mfma_f32_16x16x32_bf16(hfr[kk], fO[nt], oacc[nt], 0, 0, 0);
    if (kk < 3) {
#pragma unroll
      for (int nt = 0; nt < 8; ++nt) fO[nt] = nO[nt];
    }
  }

#pragma unroll
  for (int nt = 0; nt < 8; ++nt)
#pragma unroll
    for (int i = 0; i < 4; ++i) {
      int row = 16 * w + 4 * g + i;
      out[(chunk_t0 + row) * D_ + 16 * nt + c] = oacc[nt][i] + yx[row];
    }
}

extern "C" void kernel_launch(void* const* d_in, const int* in_sizes, int n_in,
                              void* d_out, int out_size, void* d_ws, size_t ws_size,
                              hipStream_t stream) {
  const float* x    = (const float*)d_in[0];
  const float* logA = (const float*)d_in[1];
  const float* W_B  = (const float*)d_in[2];
  const float* W_C  = (const float*)d_in[3];
  const float* W_dt = (const float*)d_in[4];
  const float* b_dt = (const float*)d_in[5];
  const float* W_out= (const float*)d_in[6];
  float* out = (float*)d_out;
  float* ws  = (float*)d_ws;

  k0_prep<<<16, 256, 0, stream>>>(W_dt, W_B, W_C, W_out, logA, ws);
  k_main<<<NCHUNK, 256, 0, stream>>>(x, b_dt, out, ws);
}